// Round 3
// baseline (295.246 us; speedup 1.0000x reference)
//
#include <hip/hip_runtime.h>

typedef unsigned short u16;
typedef unsigned int   u32;
typedef __attribute__((ext_vector_type(8))) short bf16x8;
typedef __attribute__((ext_vector_type(4))) float f32x4;
typedef __attribute__((ext_vector_type(2))) float f32x2;

#define NFEAT  256
#define NBATCH 8192
#define BT     64    // batch tile per block
#define NBT    (NBATCH / BT)   // 128

__device__ __forceinline__ u16 f2bf(float f) {
    u32 u = __builtin_bit_cast(u32, f);
    return (u16)((u + 0x7FFFu + ((u >> 16) & 1u)) >> 16);
}
__device__ __forceinline__ float bf2f(u16 h) {
    return __builtin_bit_cast(float, (u32)h << 16);
}
__device__ __forceinline__ u32 cvtpk(float a, float b) {
    u32 r;
    asm("v_cvt_pk_bf16_f32 %0, %1, %2" : "=v"(r) : "v"(a), "v"(b));
    return r;   // lo16 = bf16(a), hi16 = bf16(b), RNE
}
__device__ __forceinline__ f32x4 mfma16(bf16x8 a, bf16x8 b, f32x4 c) {
    return __builtin_amdgcn_mfma_f32_16x16x32_bf16(a, b, c, 0, 0, 0);
}

// ---------------------------------------------------------------------------
// prep: w0[f,o] = g_in[f,o] * sign(v_in[f,o,0])
// ---------------------------------------------------------------------------
__global__ void prep_w0(const float* __restrict__ v_in, const float* __restrict__ g_in,
                        u16* __restrict__ w0) {
    int i = blockIdx.x * blockDim.x + threadIdx.x;   // < 32768
    float v = v_in[i];
    float g = g_in[i];
    w0[i] = f2bf(v >= 0.f ? g : -g);
}

// ---------------------------------------------------------------------------
// prep: weight-normalize v_h0/v_h1/v_out rows -> bf16.  One wave per row.
// ---------------------------------------------------------------------------
__global__ void prep_norm(const float* __restrict__ v_h0, const float* __restrict__ g_h0,
                          const float* __restrict__ v_h1, const float* __restrict__ g_h1,
                          const float* __restrict__ v_out, const float* __restrict__ g_out,
                          u16* __restrict__ w1, u16* __restrict__ w2, u16* __restrict__ w3) {
    const int wave = (blockIdx.x * blockDim.x + threadIdx.x) >> 6;
    const int lane = threadIdx.x & 63;
    if (wave < 32768 + 16384) {
        const float* src; u16* dst; float g;
        if (wave < 32768) {
            src = v_h0 + (size_t)wave * 128; dst = w1 + (size_t)wave * 128; g = g_h0[wave];
        } else {
            int r = wave - 32768;
            src = v_h1 + (size_t)r * 128; dst = w2 + (size_t)r * 128; g = g_h1[r];
        }
        f32x2 v = *(const f32x2*)(src + lane * 2);
        float ss = v.x * v.x + v.y * v.y;
        #pragma unroll
        for (int off = 32; off; off >>= 1) ss += __shfl_xor(ss, off);
        float s = g * rsqrtf(ss);
        *(u32*)(dst + lane * 2) = cvtpk(v.x * s, v.y * s);
    } else {
        int r = wave - 49152;   // < 4096
        const float* src = v_out + (size_t)r * 64;
        float v = src[lane];
        float ss = v * v;
        #pragma unroll
        for (int off = 32; off; off >>= 1) ss += __shfl_xor(ss, off);
        float s = g_out[r] * rsqrtf(ss);
        w3[(size_t)r * 64 + lane] = f2bf(v * s);
    }
}

// ---------------------------------------------------------------------------
// prep: x_t[f][b] = bf16( tab[b,0,f] * (1 - tab[b,1,f]) )   (64x64 LDS transpose)
// ---------------------------------------------------------------------------
__global__ void prep_x(const float* __restrict__ tab, u16* __restrict__ x_t) {
    __shared__ u16 tile[64][65];
    const int bb = (blockIdx.x % (NBATCH / 64)) * 64;
    const int ff = (blockIdx.x / (NBATCH / 64)) * 64;
    const int tr = threadIdx.x >> 6;    // 0..3
    const int tc = threadIdx.x & 63;
    #pragma unroll
    for (int i = 0; i < 16; i++) {
        int b = bb + tr + i * 4;
        float val  = tab[(size_t)b * 512 + ff + tc];
        float miss = tab[(size_t)b * 512 + 256 + ff + tc];
        tile[tr + i * 4][tc] = f2bf(val * (1.f - miss));
    }
    __syncthreads();
    #pragma unroll
    for (int i = 0; i < 16; i++) {
        int fr = tr + i * 4;
        x_t[(size_t)(ff + fr) * NBATCH + bb + tc] = tile[tc][fr];
    }
}

// ---------------------------------------------------------------------------
// logits[b][j] = bias[j] + sum_f outputs[b][f][j]
// ---------------------------------------------------------------------------
__global__ void reduce_logits(const float* __restrict__ outputs,
                              const float* __restrict__ bias,
                              float* __restrict__ logits) {
    const int b = blockIdx.x * 4 + (threadIdx.x >> 6);
    const int lane = threadIdx.x & 63;
    const int j4 = lane & 3;     // output quad
    const int fo = lane >> 2;    // feature offset 0..15
    const float* base = outputs + (size_t)b * (NFEAT * 16);
    f32x4 acc = {};
    #pragma unroll
    for (int it = 0; it < 16; it++) {
        f32x4 v = *(const f32x4*)(base + (fo + it * 16) * 16 + j4 * 4);
        acc[0] += v[0]; acc[1] += v[1]; acc[2] += v[2]; acc[3] += v[3];
    }
    #pragma unroll
    for (int off = 4; off < 64; off <<= 1) {
        acc[0] += __shfl_xor(acc[0], off);
        acc[1] += __shfl_xor(acc[1], off);
        acc[2] += __shfl_xor(acc[2], off);
        acc[3] += __shfl_xor(acc[3], off);
    }
    if (lane < 4) {
        f32x4 bs = *(const f32x4*)(bias + lane * 4);
        acc[0] += bs[0]; acc[1] += bs[1]; acc[2] += bs[2]; acc[3] += bs[3];
        *(f32x4*)(logits + b * 16 + lane * 4) = acc;
    }
}

// ---------------------------------------------------------------------------
// main: per (feature f, 64-batch tile bt) block, 4 layers chained via MFMA.
// BT=64 -> 32KB LDS -> 5 blocks/CU (20 waves) for latency hiding.
// Layer0 done as rank-2 MFMA: h0 = relu([w0|b_in] . [x;1]^T).
// XCD swizzle: all 128 bt-blocks of one f on one XCD -> weights stay in L2.
// ---------------------------------------------------------------------------
__global__ __launch_bounds__(256, 5) void nam_main(
    const u16* __restrict__ x_t, const u16* __restrict__ w0g,
    const u16* __restrict__ w1g, const u16* __restrict__ w2g, const u16* __restrict__ w3g,
    const float* __restrict__ b_in, const float* __restrict__ b_h0, const float* __restrict__ b_h1,
    float* __restrict__ outputs)
{
    __shared__ u16 hA[BT * 128];   // h0 (64x128), later reused as h2 (64x64)
    __shared__ u16 hB[BT * 128];   // h1 (64x128)

    const int bid = blockIdx.x;
    const int f  = (bid & 7) * 32 + ((bid >> 3) & 31);   // XCD-contiguous features
    const int bt = bid >> 8;                             // 0..127
    const int t  = threadIdx.x;
    const int w  = t >> 6;
    const int lane = t & 63;
    const int lo = lane & 15;
    const int hi = lane >> 4;

    // ---------------- layer 0 (MFMA rank-2): h0[b][o] = relu(x[b]*w0[o]+b_in[o])
    {
        bf16x8 a[2], bm[4];
        #pragma unroll
        for (int m = 0; m < 2; m++) {
            const int o = w * 32 + m * 16 + lo;
            a[m] = bf16x8{};
            if (hi == 0) {
                a[m][0] = (short)w0g[f * 128 + o];
                a[m][1] = (short)f2bf(b_in[f * 128 + o]);
            }
        }
        #pragma unroll
        for (int n = 0; n < 4; n++) {
            const int b = n * 16 + lo;
            bm[n] = bf16x8{};
            if (hi == 0) {
                bm[n][0] = (short)x_t[(size_t)f * NBATCH + bt * BT + b];
                bm[n][1] = (short)0x3F80;   // bf16(1.0)
            }
        }
        #pragma unroll
        for (int m = 0; m < 2; m++) {
            #pragma unroll
            for (int n = 0; n < 4; n++) {
                f32x4 acc = mfma16(a[m], bm[n], f32x4{});
                const int b  = n * 16 + lo;
                const int ob = w * 32 + m * 16 + hi * 4;
                u32 p0 = cvtpk(fmaxf(0.f, acc[0]), fmaxf(0.f, acc[1]));
                u32 p1 = cvtpk(fmaxf(0.f, acc[2]), fmaxf(0.f, acc[3]));
                char* dst = (char*)hA + (((b * 128 + ob) * 2) ^ ((b & 7) << 4));
                *(uint2*)dst = make_uint2(p0, p1);
            }
        }
    }
    __syncthreads();

    // ---------------- layer 1: h1 = relu(W1 (128x128) . h0^T + b_h0) --------
    {
        f32x4 acc[2][4] = {};
        const u16* wbase = w1g + ((size_t)(f * 128 + w * 32 + lo)) * 128 + hi * 8;
        #pragma unroll
        for (int ks = 0; ks < 4; ks++) {
            bf16x8 a[2], bm[4];
            #pragma unroll
            for (int m = 0; m < 2; m++)
                a[m] = *(const bf16x8*)(wbase + m * 16 * 128 + ks * 32);
            #pragma unroll
            for (int n = 0; n < 4; n++) {
                const int b = n * 16 + lo;
                const char* p = (const char*)hA + (((b * 128 + ks * 32 + hi * 8) * 2) ^ ((b & 7) << 4));
                bm[n] = *(const bf16x8*)p;
            }
            #pragma unroll
            for (int m = 0; m < 2; m++)
                #pragma unroll
                for (int n = 0; n < 4; n++)
                    acc[m][n] = mfma16(a[m], bm[n], acc[m][n]);
        }
        #pragma unroll
        for (int m = 0; m < 2; m++) {
            const int ob = w * 32 + m * 16 + hi * 4;
            f32x4 bs = *(const f32x4*)(b_h0 + f * 128 + ob);
            #pragma unroll
            for (int n = 0; n < 4; n++) {
                const int b = n * 16 + lo;
                float r0 = fmaxf(0.f, acc[m][n][0] + bs[0]);
                float r1 = fmaxf(0.f, acc[m][n][1] + bs[1]);
                float r2 = fmaxf(0.f, acc[m][n][2] + bs[2]);
                float r3 = fmaxf(0.f, acc[m][n][3] + bs[3]);
                char* dst = (char*)hB + (((b * 128 + ob) * 2) ^ ((b & 7) << 4));
                *(uint2*)dst = make_uint2(cvtpk(r0, r1), cvtpk(r2, r3));
            }
        }
    }
    __syncthreads();

    // ---------------- layer 2: h2 = relu(W2 (64x128) . h1^T + b_h1) ---------
    // h2 stored into hA as [b][64]
    {
        f32x4 acc[4] = {};
        const u16* wbase = w2g + ((size_t)(f * 64 + w * 16 + lo)) * 128 + hi * 8;
        #pragma unroll
        for (int ks = 0; ks < 4; ks++) {
            bf16x8 a = *(const bf16x8*)(wbase + ks * 32);
            #pragma unroll
            for (int n = 0; n < 4; n++) {
                const int b = n * 16 + lo;
                const char* p = (const char*)hB + (((b * 128 + ks * 32 + hi * 8) * 2) ^ ((b & 7) << 4));
                bf16x8 bm = *(const bf16x8*)p;
                acc[n] = mfma16(a, bm, acc[n]);
            }
        }
        const int ob = w * 16 + hi * 4;
        f32x4 bs = *(const f32x4*)(b_h1 + f * 64 + ob);
        #pragma unroll
        for (int n = 0; n < 4; n++) {
            const int b = n * 16 + lo;
            float r0 = fmaxf(0.f, acc[n][0] + bs[0]);
            float r1 = fmaxf(0.f, acc[n][1] + bs[1]);
            float r2 = fmaxf(0.f, acc[n][2] + bs[2]);
            float r3 = fmaxf(0.f, acc[n][3] + bs[3]);
            char* dst = (char*)hA + (((b * 64 + ob) * 2) ^ ((b & 7) << 4));
            *(uint2*)dst = make_uint2(cvtpk(r0, r1), cvtpk(r2, r3));
        }
    }
    __syncthreads();

    // ---------------- layer 3: out = W3 (16x64) . h2^T ----------------------
    {
        f32x4 acc = {};
        const u16* wbase = w3g + ((size_t)(f * 16 + lo)) * 64 + hi * 8;
        const int b = w * 16 + lo;
        #pragma unroll
        for (int ks = 0; ks < 2; ks++) {
            bf16x8 a = *(const bf16x8*)(wbase + ks * 32);
            const char* p = (const char*)hA + (((b * 64 + ks * 32 + hi * 8) * 2) ^ ((b & 7) << 4));
            bf16x8 bm = *(const bf16x8*)p;
            acc = mfma16(a, bm, acc);
        }
        const int gb = bt * BT + b;                      // global batch row
        float* op = outputs + ((size_t)gb * NFEAT + f) * 16 + hi * 4;
        *(f32x4*)op = acc;
    }
}

// ---------------------------------------------------------------------------
extern "C" void kernel_launch(void* const* d_in, const int* in_sizes, int n_in,
                              void* d_out, int out_size, void* d_ws, size_t ws_size,
                              hipStream_t stream) {
    const float* tab   = (const float*)d_in[0];
    const float* v_in  = (const float*)d_in[1];
    const float* g_in  = (const float*)d_in[2];
    const float* b_in  = (const float*)d_in[3];
    const float* v_h0  = (const float*)d_in[4];
    const float* g_h0  = (const float*)d_in[5];
    const float* b_h0  = (const float*)d_in[6];
    const float* v_h1  = (const float*)d_in[7];
    const float* g_h1  = (const float*)d_in[8];
    const float* b_h1  = (const float*)d_in[9];
    const float* v_out = (const float*)d_in[10];
    const float* g_out = (const float*)d_in[11];
    const float* bias  = (const float*)d_in[12];

    char* ws = (char*)d_ws;
    u16* w0  = (u16*)(ws);                         //  32768 * 2
    u16* w1  = (u16*)(ws + 65536);                 // 4194304 * 2
    u16* w2  = (u16*)(ws + 65536 + 8388608);       // 2097152 * 2
    u16* w3  = (u16*)(ws + 12648448);              //  262144 * 2
    u16* x_t = (u16*)(ws + 13172736);              // 2097152 * 2  (end ~17.4MB)

    float* logits  = (float*)d_out;
    float* outputs = (float*)d_out + (size_t)NBATCH * 16;

    hipLaunchKernelGGL(prep_w0,   dim3(128),   dim3(256), 0, stream, v_in, g_in, w0);
    hipLaunchKernelGGL(prep_norm, dim3(13312), dim3(256), 0, stream,
                       v_h0, g_h0, v_h1, g_h1, v_out, g_out, w1, w2, w3);
    hipLaunchKernelGGL(prep_x,    dim3(512),   dim3(256), 0, stream, tab, x_t);
    hipLaunchKernelGGL(nam_main,  dim3(NFEAT * NBT), dim3(256), 0, stream,
                       x_t, w0, w1, w2, w3, b_in, b_h0, b_h1, outputs);
    hipLaunchKernelGGL(reduce_logits, dim3(NBATCH / 4), dim3(256), 0, stream,
                       outputs, bias, logits);
}

// Round 4
// 272.459 us; speedup vs baseline: 1.0836x; 1.0836x over previous
//
#include <hip/hip_runtime.h>

typedef unsigned short u16;
typedef unsigned int   u32;
typedef __attribute__((ext_vector_type(8))) short bf16x8;
typedef __attribute__((ext_vector_type(4))) float f32x4;
typedef __attribute__((ext_vector_type(2))) float f32x2;

#define NFEAT  256
#define NBATCH 8192
#define BT     64    // batch tile per block
#define NBT    (NBATCH / BT)   // 128

__device__ __forceinline__ u16 f2bf(float f) {
    u32 u = __builtin_bit_cast(u32, f);
    return (u16)((u + 0x7FFFu + ((u >> 16) & 1u)) >> 16);
}
__device__ __forceinline__ float bf2f(u16 h) {
    return __builtin_bit_cast(float, (u32)h << 16);
}
__device__ __forceinline__ u32 cvtpk(float a, float b) {
    u32 r;
    asm("v_cvt_pk_bf16_f32 %0, %1, %2" : "=v"(r) : "v"(a), "v"(b));
    return r;   // lo16 = bf16(a), hi16 = bf16(b), RNE
}
__device__ __forceinline__ f32x4 mfma16(bf16x8 a, bf16x8 b, f32x4 c) {
    return __builtin_amdgcn_mfma_f32_16x16x32_bf16(a, b, c, 0, 0, 0);
}
__device__ __forceinline__ bf16x8 frag_word0(u32 word0) {
    union { bf16x8 v; u32 w[4]; } u;
    u.w[0] = word0; u.w[1] = 0; u.w[2] = 0; u.w[3] = 0;
    return u.v;
}

// ---------------------------------------------------------------------------
// prep: w0[f,o] = g_in[f,o] * sign(v_in[f,o,0])
// ---------------------------------------------------------------------------
__global__ void prep_w0(const float* __restrict__ v_in, const float* __restrict__ g_in,
                        u16* __restrict__ w0) {
    int i = blockIdx.x * blockDim.x + threadIdx.x;   // < 32768
    float v = v_in[i];
    float g = g_in[i];
    w0[i] = f2bf(v >= 0.f ? g : -g);
}

// ---------------------------------------------------------------------------
// prep: weight-normalize v_h0/v_h1/v_out rows -> bf16.  One wave per row.
// ---------------------------------------------------------------------------
__global__ void prep_norm(const float* __restrict__ v_h0, const float* __restrict__ g_h0,
                          const float* __restrict__ v_h1, const float* __restrict__ g_h1,
                          const float* __restrict__ v_out, const float* __restrict__ g_out,
                          u16* __restrict__ w1, u16* __restrict__ w2, u16* __restrict__ w3) {
    const int wave = (blockIdx.x * blockDim.x + threadIdx.x) >> 6;
    const int lane = threadIdx.x & 63;
    if (wave < 32768 + 16384) {
        const float* src; u16* dst; float g;
        if (wave < 32768) {
            src = v_h0 + (size_t)wave * 128; dst = w1 + (size_t)wave * 128; g = g_h0[wave];
        } else {
            int r = wave - 32768;
            src = v_h1 + (size_t)r * 128; dst = w2 + (size_t)r * 128; g = g_h1[r];
        }
        f32x2 v = *(const f32x2*)(src + lane * 2);
        float ss = v.x * v.x + v.y * v.y;
        #pragma unroll
        for (int off = 32; off; off >>= 1) ss += __shfl_xor(ss, off);
        float s = g * rsqrtf(ss);
        *(u32*)(dst + lane * 2) = cvtpk(v.x * s, v.y * s);
    } else {
        int r = wave - 49152;   // < 4096
        const float* src = v_out + (size_t)r * 64;
        float v = src[lane];
        float ss = v * v;
        #pragma unroll
        for (int off = 32; off; off >>= 1) ss += __shfl_xor(ss, off);
        float s = g_out[r] * rsqrtf(ss);
        w3[(size_t)r * 64 + lane] = f2bf(v * s);
    }
}

// ---------------------------------------------------------------------------
// prep: x_t[f][b] = bf16( tab[b,0,f] * (1 - tab[b,1,f]) )   (64x64 LDS transpose)
// ---------------------------------------------------------------------------
__global__ void prep_x(const float* __restrict__ tab, u16* __restrict__ x_t) {
    __shared__ u16 tile[64][65];
    const int bb = (blockIdx.x % (NBATCH / 64)) * 64;
    const int ff = (blockIdx.x / (NBATCH / 64)) * 64;
    const int tr = threadIdx.x >> 6;    // 0..3
    const int tc = threadIdx.x & 63;
    #pragma unroll
    for (int i = 0; i < 16; i++) {
        int b = bb + tr + i * 4;
        float val  = tab[(size_t)b * 512 + ff + tc];
        float miss = tab[(size_t)b * 512 + 256 + ff + tc];
        tile[tr + i * 4][tc] = f2bf(val * (1.f - miss));
    }
    __syncthreads();
    #pragma unroll
    for (int i = 0; i < 16; i++) {
        int fr = tr + i * 4;
        x_t[(size_t)(ff + fr) * NBATCH + bb + tc] = tile[tc][fr];
    }
}

// ---------------------------------------------------------------------------
// logits[b][j] = bias[j] + sum_f outputs[b][f][j]
// ---------------------------------------------------------------------------
__global__ void reduce_logits(const float* __restrict__ outputs,
                              const float* __restrict__ bias,
                              float* __restrict__ logits) {
    const int b = blockIdx.x * 4 + (threadIdx.x >> 6);
    const int lane = threadIdx.x & 63;
    const int j4 = lane & 3;     // output quad
    const int fo = lane >> 2;    // feature offset 0..15
    const float* base = outputs + (size_t)b * (NFEAT * 16);
    f32x4 acc = {};
    #pragma unroll
    for (int it = 0; it < 16; it++) {
        f32x4 v = *(const f32x4*)(base + (fo + it * 16) * 16 + j4 * 4);
        acc[0] += v[0]; acc[1] += v[1]; acc[2] += v[2]; acc[3] += v[3];
    }
    #pragma unroll
    for (int off = 4; off < 64; off <<= 1) {
        acc[0] += __shfl_xor(acc[0], off);
        acc[1] += __shfl_xor(acc[1], off);
        acc[2] += __shfl_xor(acc[2], off);
        acc[3] += __shfl_xor(acc[3], off);
    }
    if (lane < 4) {
        f32x4 bs = *(const f32x4*)(bias + lane * 4);
        acc[0] += bs[0]; acc[1] += bs[1]; acc[2] += bs[2]; acc[3] += bs[3];
        *(f32x4*)(logits + b * 16 + lane * 4) = acc;
    }
}

// ---------------------------------------------------------------------------
// main: 2-wave blocks (128 thr), BT=64.  Each wave owns a 64o x 64b acc tile
// in L1 (minimal LDS bytes/MAC); all weight fragments preloaded to VGPRs
// before layer 0 so L2-cache latency hides under L0+barriers.
// Layer0 = rank-2 MFMA with cheap packed-word fragment build.
// XCD swizzle keeps each feature's weight set resident in one XCD's L2.
// ---------------------------------------------------------------------------
__global__ __launch_bounds__(128, 2) void nam_main(
    const u16* __restrict__ x_t, const u16* __restrict__ w0g,
    const u16* __restrict__ w1g, const u16* __restrict__ w2g, const u16* __restrict__ w3g,
    const float* __restrict__ b_in, const float* __restrict__ b_h0, const float* __restrict__ b_h1,
    float* __restrict__ outputs)
{
    __shared__ u16 hA[BT * 128];   // h0 (64x128), later reused as h2 (64x64)
    __shared__ u16 hB[BT * 128];   // h1 (64x128)

    const int bid = blockIdx.x;
    const int f  = (bid & 7) * 32 + ((bid >> 3) & 31);   // XCD-contiguous features
    const int bt = bid >> 8;                             // 0..127
    const int t  = threadIdx.x;
    const int w  = t >> 6;          // 0..1
    const int lane = t & 63;
    const int lo = lane & 15;
    const int hi = lane >> 4;

    // ---- layer-0 input loads first (so their waitcnt doesn't drain W-frags)
    u32 xw[4], w0w[4];
    float biw[4];
    #pragma unroll
    for (int n = 0; n < 4; n++)
        xw[n] = (u32)x_t[(size_t)f * NBATCH + bt * BT + n * 16 + lo];
    #pragma unroll
    for (int m = 0; m < 4; m++) {
        const int o = f * 128 + w * 64 + m * 16 + lo;
        w0w[m] = (u32)w0g[o];
        biw[m] = b_in[o];
    }

    // ---- preload ALL weight fragments into VGPRs (A-operands, from L2) ----
    bf16x8 w1f[4][4];   // o = w*64 + m*16 + lo, k = ks*32 + hi*8
    {
        const u16* base = w1g + ((size_t)(f * 128 + w * 64 + lo)) * 128 + hi * 8;
        #pragma unroll
        for (int m = 0; m < 4; m++)
            #pragma unroll
            for (int ks = 0; ks < 4; ks++)
                w1f[m][ks] = *(const bf16x8*)(base + m * 16 * 128 + ks * 32);
    }
    bf16x8 w2f[2][4];   // o = w*32 + m*16 + lo
    {
        const u16* base = w2g + ((size_t)(f * 64 + w * 32 + lo)) * 128 + hi * 8;
        #pragma unroll
        for (int m = 0; m < 2; m++)
            #pragma unroll
            for (int ks = 0; ks < 4; ks++)
                w2f[m][ks] = *(const bf16x8*)(base + m * 16 * 128 + ks * 32);
    }
    bf16x8 w3f[2];      // o = lo (16 rows)
    {
        const u16* base = w3g + ((size_t)(f * 16 + lo)) * 64 + hi * 8;
        #pragma unroll
        for (int ks = 0; ks < 2; ks++)
            w3f[ks] = *(const bf16x8*)(base + ks * 32);
    }

    // ---------------- layer 0 (rank-2 MFMA): h0[o][b] = relu(w0[o]*x[b]+b_in[o])
    {
        bf16x8 a[4], bm[4];
        #pragma unroll
        for (int m = 0; m < 4; m++) {
            u32 pk = w0w[m] | (cvtpk(biw[m], biw[m]) << 16);   // {w0, bf(b_in)}
            a[m] = frag_word0(hi == 0 ? pk : 0u);
        }
        #pragma unroll
        for (int n = 0; n < 4; n++) {
            u32 pk = xw[n] | 0x3F800000u;                       // {x, 1.0bf}
            bm[n] = frag_word0(hi == 0 ? pk : 0u);
        }
        #pragma unroll
        for (int m = 0; m < 4; m++) {
            #pragma unroll
            for (int n = 0; n < 4; n++) {
                f32x4 d = mfma16(a[m], bm[n], f32x4{});
                const int b = n * 16 + lo;
                const int col2 = (w * 64 + m * 16 + hi * 4) * 2;
                char* dst = (char*)hA + b * 256 + (col2 ^ ((b & 7) << 4));
                *(uint2*)dst = make_uint2(cvtpk(fmaxf(0.f, d[0]), fmaxf(0.f, d[1])),
                                          cvtpk(fmaxf(0.f, d[2]), fmaxf(0.f, d[3])));
            }
        }
    }
    __syncthreads();

    // ---------------- layer 1: h1 = relu(W1 (128x128) . h0^T + b_h0) --------
    // wave tile: 64 o x 64 b  (acc[4][4])
    {
        f32x4 acc[4][4] = {};
        #pragma unroll
        for (int ks = 0; ks < 4; ks++) {
            bf16x8 bm[4];
            #pragma unroll
            for (int n = 0; n < 4; n++) {
                const int b = n * 16 + lo;
                const char* p = (const char*)hA + b * 256 + ((ks * 64 + hi * 16) ^ ((b & 7) << 4));
                bm[n] = *(const bf16x8*)p;
            }
            __builtin_amdgcn_s_setprio(1);
            #pragma unroll
            for (int m = 0; m < 4; m++)
                #pragma unroll
                for (int n = 0; n < 4; n++)
                    acc[m][n] = mfma16(w1f[m][ks], bm[n], acc[m][n]);
            __builtin_amdgcn_s_setprio(0);
        }
        #pragma unroll
        for (int m = 0; m < 4; m++) {
            const int ob = w * 64 + m * 16 + hi * 4;
            f32x4 bs = *(const f32x4*)(b_h0 + f * 128 + ob);
            #pragma unroll
            for (int n = 0; n < 4; n++) {
                const int b = n * 16 + lo;
                float r0 = fmaxf(0.f, acc[m][n][0] + bs[0]);
                float r1 = fmaxf(0.f, acc[m][n][1] + bs[1]);
                float r2 = fmaxf(0.f, acc[m][n][2] + bs[2]);
                float r3 = fmaxf(0.f, acc[m][n][3] + bs[3]);
                char* dst = (char*)hB + b * 256 + ((ob * 2) ^ ((b & 7) << 4));
                *(uint2*)dst = make_uint2(cvtpk(r0, r1), cvtpk(r2, r3));
            }
        }
    }
    __syncthreads();

    // ---------------- layer 2: h2 = relu(W2 (64x128) . h1^T + b_h1) ---------
    // wave tile: 32 o x 64 b;  h2 -> hA as [b][64] (128B rows)
    {
        f32x4 acc[2][4] = {};
        #pragma unroll
        for (int ks = 0; ks < 4; ks++) {
            bf16x8 bm[4];
            #pragma unroll
            for (int n = 0; n < 4; n++) {
                const int b = n * 16 + lo;
                const char* p = (const char*)hB + b * 256 + ((ks * 64 + hi * 16) ^ ((b & 7) << 4));
                bm[n] = *(const bf16x8*)p;
            }
            __builtin_amdgcn_s_setprio(1);
            #pragma unroll
            for (int m = 0; m < 2; m++)
                #pragma unroll
                for (int n = 0; n < 4; n++)
                    acc[m][n] = mfma16(w2f[m][ks], bm[n], acc[m][n]);
            __builtin_amdgcn_s_setprio(0);
        }
        #pragma unroll
        for (int m = 0; m < 2; m++) {
            const int ob = w * 32 + m * 16 + hi * 4;
            f32x4 bs = *(const f32x4*)(b_h1 + f * 64 + ob);
            #pragma unroll
            for (int n = 0; n < 4; n++) {
                const int b = n * 16 + lo;
                float r0 = fmaxf(0.f, acc[m][n][0] + bs[0]);
                float r1 = fmaxf(0.f, acc[m][n][1] + bs[1]);
                float r2 = fmaxf(0.f, acc[m][n][2] + bs[2]);
                float r3 = fmaxf(0.f, acc[m][n][3] + bs[3]);
                char* dst = (char*)hA + b * 128 + ((ob * 2) ^ ((b & 7) << 4));
                *(uint2*)dst = make_uint2(cvtpk(r0, r1), cvtpk(r2, r3));
            }
        }
    }
    __syncthreads();

    // ---------------- layer 3: out = W3 (16x64) . h2^T ----------------------
    // wave covers 32 b (n=0..1)
    {
        f32x4 acc[2] = {};
        #pragma unroll
        for (int ks = 0; ks < 2; ks++) {
            #pragma unroll
            for (int n = 0; n < 2; n++) {
                const int b = w * 32 + n * 16 + lo;
                const char* p = (const char*)hA + b * 128 + ((ks * 64 + hi * 16) ^ ((b & 7) << 4));
                bf16x8 bm = *(const bf16x8*)p;
                acc[n] = mfma16(w3f[ks], bm, acc[n]);
            }
        }
        #pragma unroll
        for (int n = 0; n < 2; n++) {
            const int gb = bt * BT + w * 32 + n * 16 + lo;   // global batch row
            float* op = outputs + ((size_t)gb * NFEAT + f) * 16 + hi * 4;
            *(f32x4*)op = acc[n];
        }
    }
}

// ---------------------------------------------------------------------------
extern "C" void kernel_launch(void* const* d_in, const int* in_sizes, int n_in,
                              void* d_out, int out_size, void* d_ws, size_t ws_size,
                              hipStream_t stream) {
    const float* tab   = (const float*)d_in[0];
    const float* v_in  = (const float*)d_in[1];
    const float* g_in  = (const float*)d_in[2];
    const float* b_in  = (const float*)d_in[3];
    const float* v_h0  = (const float*)d_in[4];
    const float* g_h0  = (const float*)d_in[5];
    const float* b_h0  = (const float*)d_in[6];
    const float* v_h1  = (const float*)d_in[7];
    const float* g_h1  = (const float*)d_in[8];
    const float* b_h1  = (const float*)d_in[9];
    const float* v_out = (const float*)d_in[10];
    const float* g_out = (const float*)d_in[11];
    const float* bias  = (const float*)d_in[12];

    char* ws = (char*)d_ws;
    u16* w0  = (u16*)(ws);                         //  32768 * 2
    u16* w1  = (u16*)(ws + 65536);                 // 4194304 * 2
    u16* w2  = (u16*)(ws + 65536 + 8388608);       // 2097152 * 2
    u16* w3  = (u16*)(ws + 12648448);              //  262144 * 2
    u16* x_t = (u16*)(ws + 13172736);              // 2097152 * 2  (end ~17.4MB)

    float* logits  = (float*)d_out;
    float* outputs = (float*)d_out + (size_t)NBATCH * 16;

    hipLaunchKernelGGL(prep_w0,   dim3(128),   dim3(256), 0, stream, v_in, g_in, w0);
    hipLaunchKernelGGL(prep_norm, dim3(13312), dim3(256), 0, stream,
                       v_h0, g_h0, v_h1, g_h1, v_out, g_out, w1, w2, w3);
    hipLaunchKernelGGL(prep_x,    dim3(512),   dim3(256), 0, stream, tab, x_t);
    hipLaunchKernelGGL(nam_main,  dim3(NFEAT * NBT), dim3(128), 0, stream,
                       x_t, w0, w1, w2, w3, b_in, b_h0, b_h1, outputs);
    hipLaunchKernelGGL(reduce_logits, dim3(NBATCH / 4), dim3(256), 0, stream,
                       outputs, bias, logits);
}

// Round 5
// 180.632 us; speedup vs baseline: 1.6345x; 1.5084x over previous
//
#include <hip/hip_runtime.h>

typedef unsigned short u16;
typedef unsigned int   u32;
typedef __attribute__((ext_vector_type(8))) short bf16x8;
typedef __attribute__((ext_vector_type(4))) float f32x4;
typedef __attribute__((ext_vector_type(2))) float f32x2;

#define NFEAT  256
#define NBATCH 8192
#define BT     64    // batch tile per iteration
#define NBT    (NBATCH / BT)   // 128
#define ITERS  8     // bt-iterations per persistent block

__device__ __forceinline__ u16 f2bf(float f) {
    u32 u = __builtin_bit_cast(u32, f);
    return (u16)((u + 0x7FFFu + ((u >> 16) & 1u)) >> 16);
}
__device__ __forceinline__ u32 cvtpk(float a, float b) {
    u32 r;
    asm("v_cvt_pk_bf16_f32 %0, %1, %2" : "=v"(r) : "v"(a), "v"(b));
    return r;   // lo16 = bf16(a), hi16 = bf16(b), RNE
}
__device__ __forceinline__ f32x4 mfma16(bf16x8 a, bf16x8 b, f32x4 c) {
    return __builtin_amdgcn_mfma_f32_16x16x32_bf16(a, b, c, 0, 0, 0);
}
__device__ __forceinline__ bf16x8 frag_word0(u32 word0) {
    union { bf16x8 v; u32 w[4]; } u;
    u.w[0] = word0; u.w[1] = 0; u.w[2] = 0; u.w[3] = 0;
    return u.v;
}
// conflict-free LDS addressing: 256B rows, 4-bit slot swizzle (bijective)
__device__ __forceinline__ char* swz(char* base, int b, int col2) {
    return base + b * 256 + (col2 ^ ((b & 15) << 4));
}
__device__ __forceinline__ const char* swz(const char* base, int b, int col2) {
    return base + b * 256 + (col2 ^ ((b & 15) << 4));
}

// ---------------------------------------------------------------------------
// prep: w0[f,o] = g_in[f,o] * sign(v_in[f,o,0])
// ---------------------------------------------------------------------------
__global__ void prep_w0(const float* __restrict__ v_in, const float* __restrict__ g_in,
                        u16* __restrict__ w0) {
    int i = blockIdx.x * blockDim.x + threadIdx.x;   // < 32768
    float v = v_in[i];
    float g = g_in[i];
    w0[i] = f2bf(v >= 0.f ? g : -g);
}

// ---------------------------------------------------------------------------
// prep: weight-normalize v_h0/v_h1/v_out rows -> bf16.  One wave per row.
// ---------------------------------------------------------------------------
__global__ void prep_norm(const float* __restrict__ v_h0, const float* __restrict__ g_h0,
                          const float* __restrict__ v_h1, const float* __restrict__ g_h1,
                          const float* __restrict__ v_out, const float* __restrict__ g_out,
                          u16* __restrict__ w1, u16* __restrict__ w2, u16* __restrict__ w3) {
    const int wave = (blockIdx.x * blockDim.x + threadIdx.x) >> 6;
    const int lane = threadIdx.x & 63;
    if (wave < 32768 + 16384) {
        const float* src; u16* dst; float g;
        if (wave < 32768) {
            src = v_h0 + (size_t)wave * 128; dst = w1 + (size_t)wave * 128; g = g_h0[wave];
        } else {
            int r = wave - 32768;
            src = v_h1 + (size_t)r * 128; dst = w2 + (size_t)r * 128; g = g_h1[r];
        }
        f32x2 v = *(const f32x2*)(src + lane * 2);
        float ss = v.x * v.x + v.y * v.y;
        #pragma unroll
        for (int off = 32; off; off >>= 1) ss += __shfl_xor(ss, off);
        float s = g * rsqrtf(ss);
        *(u32*)(dst + lane * 2) = cvtpk(v.x * s, v.y * s);
    } else {
        int r = wave - 49152;   // < 4096
        const float* src = v_out + (size_t)r * 64;
        float v = src[lane];
        float ss = v * v;
        #pragma unroll
        for (int off = 32; off; off >>= 1) ss += __shfl_xor(ss, off);
        float s = g_out[r] * rsqrtf(ss);
        w3[(size_t)r * 64 + lane] = f2bf(v * s);
    }
}

// ---------------------------------------------------------------------------
// prep: x_t[f][b] = bf16( tab[b,0,f] * (1 - tab[b,1,f]) )   (64x64 LDS transpose)
// ---------------------------------------------------------------------------
__global__ void prep_x(const float* __restrict__ tab, u16* __restrict__ x_t) {
    __shared__ u16 tile[64][65];
    const int bb = (blockIdx.x % (NBATCH / 64)) * 64;
    const int ff = (blockIdx.x / (NBATCH / 64)) * 64;
    const int tr = threadIdx.x >> 6;    // 0..3
    const int tc = threadIdx.x & 63;
    #pragma unroll
    for (int i = 0; i < 16; i++) {
        int b = bb + tr + i * 4;
        float val  = tab[(size_t)b * 512 + ff + tc];
        float miss = tab[(size_t)b * 512 + 256 + ff + tc];
        tile[tr + i * 4][tc] = f2bf(val * (1.f - miss));
    }
    __syncthreads();
    #pragma unroll
    for (int i = 0; i < 16; i++) {
        int fr = tr + i * 4;
        x_t[(size_t)(ff + fr) * NBATCH + bb + tc] = tile[tc][fr];
    }
}

// ---------------------------------------------------------------------------
// logits[b][j] = bias[j] + sum_f outputs[b][f][j]
// ---------------------------------------------------------------------------
__global__ void reduce_logits(const float* __restrict__ outputs,
                              const float* __restrict__ bias,
                              float* __restrict__ logits) {
    const int b = blockIdx.x * 4 + (threadIdx.x >> 6);
    const int lane = threadIdx.x & 63;
    const int j4 = lane & 3;     // output quad
    const int fo = lane >> 2;    // feature offset 0..15
    const float* base = outputs + (size_t)b * (NFEAT * 16);
    f32x4 acc = {};
    #pragma unroll
    for (int it = 0; it < 16; it++) {
        f32x4 v = *(const f32x4*)(base + (fo + it * 16) * 16 + j4 * 4);
        acc[0] += v[0]; acc[1] += v[1]; acc[2] += v[2]; acc[3] += v[3];
    }
    #pragma unroll
    for (int off = 4; off < 64; off <<= 1) {
        acc[0] += __shfl_xor(acc[0], off);
        acc[1] += __shfl_xor(acc[1], off);
        acc[2] += __shfl_xor(acc[2], off);
        acc[3] += __shfl_xor(acc[3], off);
    }
    if (lane < 4) {
        f32x4 bs = *(const f32x4*)(bias + lane * 4);
        acc[0] += bs[0]; acc[1] += bs[1]; acc[2] += bs[2]; acc[3] += bs[3];
        *(f32x4*)(logits + b * 16 + lane * 4) = acc;
    }
}

// ---------------------------------------------------------------------------
// main: persistent-f blocks.  Grid 4096 x 128 thr; block = (xcd, fi, chunk),
// keeps one feature's weights+biases in registers across ITERS=8 bt-tiles.
// Per iter: L0 rank-2 MFMA -> hA, L1 (128x128) -> hB, L2 (64x128) -> hA,
// L3 (16x64) -> global.  2 waves split the o-dim; activations via LDS with
// conflict-free 4-bit swizzle (256B rows).
// ---------------------------------------------------------------------------
__global__ __launch_bounds__(128, 2) void nam_main(
    const u16* __restrict__ x_t, const u16* __restrict__ w0g,
    const u16* __restrict__ w1g, const u16* __restrict__ w2g, const u16* __restrict__ w3g,
    const float* __restrict__ b_in, const float* __restrict__ b_h0, const float* __restrict__ b_h1,
    float* __restrict__ outputs)
{
    __shared__ u16 hA[BT * 128];   // h0 (64 x 256B rows), later h2 (64 x 256B rows)
    __shared__ u16 hB[BT * 128];   // h1 (64 x 256B rows)

    const int bid   = blockIdx.x;
    const int f     = (bid & 7) * 32 + ((bid >> 3) & 31);  // XCD-contiguous features
    const int chunk = bid >> 8;                            // 0..15
    const int t  = threadIdx.x;
    const int w  = t >> 6;          // 0..1 (o-half)
    const int lane = t & 63;
    const int lo = lane & 15;
    const int hi = lane >> 4;

    // ---- per-feature constants: weights + biases, loaded once ----
    u32 w0w[4];  float biw[4];
    #pragma unroll
    for (int m = 0; m < 4; m++) {
        const int o = f * 128 + w * 64 + m * 16 + lo;
        w0w[m] = (u32)w0g[o];
        biw[m] = b_in[o];
    }
    bf16x8 w1f[4][4];   // o = w*64 + m*16 + lo, k = ks*32 + hi*8
    {
        const u16* base = w1g + ((size_t)(f * 128 + w * 64 + lo)) * 128 + hi * 8;
        #pragma unroll
        for (int m = 0; m < 4; m++)
            #pragma unroll
            for (int ks = 0; ks < 4; ks++)
                w1f[m][ks] = *(const bf16x8*)(base + m * 16 * 128 + ks * 32);
    }
    bf16x8 w2f[2][4];   // o = w*32 + m*16 + lo
    {
        const u16* base = w2g + ((size_t)(f * 64 + w * 32 + lo)) * 128 + hi * 8;
        #pragma unroll
        for (int m = 0; m < 2; m++)
            #pragma unroll
            for (int ks = 0; ks < 4; ks++)
                w2f[m][ks] = *(const bf16x8*)(base + m * 16 * 128 + ks * 32);
    }
    bf16x8 w3f[2];      // o = lo (16 rows)
    {
        const u16* base = w3g + ((size_t)(f * 16 + lo)) * 64 + hi * 8;
        #pragma unroll
        for (int ks = 0; ks < 2; ks++)
            w3f[ks] = *(const bf16x8*)(base + ks * 32);
    }
    f32x4 bs1[4];   // b_h0 for ob = w*64 + m*16 + hi*4
    #pragma unroll
    for (int m = 0; m < 4; m++)
        bs1[m] = *(const f32x4*)(b_h0 + f * 128 + w * 64 + m * 16 + hi * 4);
    f32x4 bs2[2];   // b_h1 for ob = w*32 + m*16 + hi*4
    #pragma unroll
    for (int m = 0; m < 2; m++)
        bs2[m] = *(const f32x4*)(b_h1 + f * 64 + w * 32 + m * 16 + hi * 4);
    // L0 A-frags are loop-invariant too
    bf16x8 a0[4];
    #pragma unroll
    for (int m = 0; m < 4; m++) {
        u32 pk = w0w[m] | (cvtpk(biw[m], biw[m]) << 16);   // {w0, bf16(b_in)}
        a0[m] = frag_word0(hi == 0 ? pk : 0u);
    }

    for (int it = 0; it < ITERS; it++) {
        const int bt = chunk * ITERS + it;
        // layer-0 inputs for this tile
        u32 xw[4];
        #pragma unroll
        for (int n = 0; n < 4; n++)
            xw[n] = (u32)x_t[(size_t)f * NBATCH + bt * BT + n * 16 + lo];

        __syncthreads();   // prev iter's L3 reads of hA complete

        // ---------- layer 0 (rank-2 MFMA): h0[o][b] = relu(w0[o]*x[b]+b_in[o])
        {
            bf16x8 bm[4];
            #pragma unroll
            for (int n = 0; n < 4; n++) {
                u32 pk = xw[n] | 0x3F800000u;               // {x, 1.0bf}
                bm[n] = frag_word0(hi == 0 ? pk : 0u);
            }
            #pragma unroll
            for (int m = 0; m < 4; m++) {
                #pragma unroll
                for (int n = 0; n < 4; n++) {
                    f32x4 d = mfma16(a0[m], bm[n], f32x4{});
                    const int b = n * 16 + lo;
                    const int col2 = (w * 64 + m * 16 + hi * 4) * 2;
                    *(uint2*)swz((char*)hA, b, col2) =
                        make_uint2(cvtpk(fmaxf(0.f, d[0]), fmaxf(0.f, d[1])),
                                   cvtpk(fmaxf(0.f, d[2]), fmaxf(0.f, d[3])));
                }
            }
        }
        __syncthreads();

        // ---------- layer 1: h1 = relu(W1 (128x128) . h0^T + b_h0) ----------
        {
            f32x4 acc[4][4] = {};
            #pragma unroll
            for (int ks = 0; ks < 4; ks++) {
                bf16x8 bm[4];
                #pragma unroll
                for (int n = 0; n < 4; n++) {
                    const int b = n * 16 + lo;
                    bm[n] = *(const bf16x8*)swz((const char*)hA, b, ks * 64 + hi * 16);
                }
                __builtin_amdgcn_s_setprio(1);
                #pragma unroll
                for (int m = 0; m < 4; m++)
                    #pragma unroll
                    for (int n = 0; n < 4; n++)
                        acc[m][n] = mfma16(w1f[m][ks], bm[n], acc[m][n]);
                __builtin_amdgcn_s_setprio(0);
            }
            #pragma unroll
            for (int m = 0; m < 4; m++) {
                const int col2 = (w * 64 + m * 16 + hi * 4) * 2;
                #pragma unroll
                for (int n = 0; n < 4; n++) {
                    const int b = n * 16 + lo;
                    float r0 = fmaxf(0.f, acc[m][n][0] + bs1[m][0]);
                    float r1 = fmaxf(0.f, acc[m][n][1] + bs1[m][1]);
                    float r2 = fmaxf(0.f, acc[m][n][2] + bs1[m][2]);
                    float r3 = fmaxf(0.f, acc[m][n][3] + bs1[m][3]);
                    *(uint2*)swz((char*)hB, b, col2) =
                        make_uint2(cvtpk(r0, r1), cvtpk(r2, r3));
                }
            }
        }
        __syncthreads();

        // ---------- layer 2: h2 = relu(W2 (64x128) . h1^T + b_h1) -----------
        // h2 -> hA, 256B-stride rows (64 cols used)
        {
            f32x4 acc[2][4] = {};
            #pragma unroll
            for (int ks = 0; ks < 4; ks++) {
                bf16x8 bm[4];
                #pragma unroll
                for (int n = 0; n < 4; n++) {
                    const int b = n * 16 + lo;
                    bm[n] = *(const bf16x8*)swz((const char*)hB, b, ks * 64 + hi * 16);
                }
                __builtin_amdgcn_s_setprio(1);
                #pragma unroll
                for (int m = 0; m < 2; m++)
                    #pragma unroll
                    for (int n = 0; n < 4; n++)
                        acc[m][n] = mfma16(w2f[m][ks], bm[n], acc[m][n]);
                __builtin_amdgcn_s_setprio(0);
            }
            #pragma unroll
            for (int m = 0; m < 2; m++) {
                const int col2 = (w * 32 + m * 16 + hi * 4) * 2;
                #pragma unroll
                for (int n = 0; n < 4; n++) {
                    const int b = n * 16 + lo;
                    float r0 = fmaxf(0.f, acc[m][n][0] + bs2[m][0]);
                    float r1 = fmaxf(0.f, acc[m][n][1] + bs2[m][1]);
                    float r2 = fmaxf(0.f, acc[m][n][2] + bs2[m][2]);
                    float r3 = fmaxf(0.f, acc[m][n][3] + bs2[m][3]);
                    *(uint2*)swz((char*)hA, b, col2) =
                        make_uint2(cvtpk(r0, r1), cvtpk(r2, r3));
                }
            }
        }
        __syncthreads();

        // ---------- layer 3: out = W3 (16x64) . h2^T ------------------------
        {
            f32x4 acc[2] = {};
            #pragma unroll
            for (int ks = 0; ks < 2; ks++) {
                #pragma unroll
                for (int n = 0; n < 2; n++) {
                    const int b = w * 32 + n * 16 + lo;
                    bf16x8 bm = *(const bf16x8*)swz((const char*)hA, b, ks * 64 + hi * 16);
                    acc[n] = mfma16(w3f[ks], bm, acc[n]);
                }
            }
            #pragma unroll
            for (int n = 0; n < 2; n++) {
                const int gb = bt * BT + w * 32 + n * 16 + lo;   // global batch row
                float* op = outputs + ((size_t)gb * NFEAT + f) * 16 + hi * 4;
                *(f32x4*)op = acc[n];
            }
        }
    }
}

// ---------------------------------------------------------------------------
extern "C" void kernel_launch(void* const* d_in, const int* in_sizes, int n_in,
                              void* d_out, int out_size, void* d_ws, size_t ws_size,
                              hipStream_t stream) {
    const float* tab   = (const float*)d_in[0];
    const float* v_in  = (const float*)d_in[1];
    const float* g_in  = (const float*)d_in[2];
    const float* b_in  = (const float*)d_in[3];
    const float* v_h0  = (const float*)d_in[4];
    const float* g_h0  = (const float*)d_in[5];
    const float* b_h0  = (const float*)d_in[6];
    const float* v_h1  = (const float*)d_in[7];
    const float* g_h1  = (const float*)d_in[8];
    const float* b_h1  = (const float*)d_in[9];
    const float* v_out = (const float*)d_in[10];
    const float* g_out = (const float*)d_in[11];
    const float* bias  = (const float*)d_in[12];

    char* ws = (char*)d_ws;
    u16* w0  = (u16*)(ws);                         //  32768 * 2
    u16* w1  = (u16*)(ws + 65536);                 // 4194304 * 2
    u16* w2  = (u16*)(ws + 65536 + 8388608);       // 2097152 * 2
    u16* w3  = (u16*)(ws + 12648448);              //  262144 * 2
    u16* x_t = (u16*)(ws + 13172736);              // 2097152 * 2  (end ~17.4MB)

    float* logits  = (float*)d_out;
    float* outputs = (float*)d_out + (size_t)NBATCH * 16;

    hipLaunchKernelGGL(prep_w0,   dim3(128),   dim3(256), 0, stream, v_in, g_in, w0);
    hipLaunchKernelGGL(prep_norm, dim3(13312), dim3(256), 0, stream,
                       v_h0, g_h0, v_h1, g_h1, v_out, g_out, w1, w2, w3);
    hipLaunchKernelGGL(prep_x,    dim3(512),   dim3(256), 0, stream, tab, x_t);
    hipLaunchKernelGGL(nam_main,  dim3(NFEAT * NBT / ITERS), dim3(128), 0, stream,
                       x_t, w0, w1, w2, w3, b_in, b_h0, b_h1, outputs);
    hipLaunchKernelGGL(reduce_logits, dim3(NBATCH / 4), dim3(256), 0, stream,
                       outputs, bias, logits);
}